// Round 6
// baseline (351.960 us; speedup 1.0000x reference)
//
#include <hip/hip_runtime.h>
#include <hip/hip_bf16.h>
#include <math.h>

#define NN 50000
#define NE 600000
#define NF 256
#define NHID 128
#define HEADS 8
#define D0 16
#define NCLS 64
#define NB1 196  // (NN+255)/256

#define PK0 (9 * 8 * 64 * 8)   // Bp0: 8 col-tiles of W0 + 1 alpha tile (W0A)
#define PK1 (4 * 32 * 64 * 8)  // Bp1
#define PKA (4 * 64 * 8)       // wA1b: K=128, N=16 (cols 0-7 wS heads, 8-15 wD)
#define CASTN (NN * NF / 4)    // 3.2M float4 groups
#define PREPN (PK0 + PK1 + PKA)

typedef __attribute__((ext_vector_type(8))) short short8;
typedef __attribute__((ext_vector_type(4))) float floatx4;

__device__ __forceinline__ float bf16lo(uint v) { return __uint_as_float((v & 0xffffu) << 16); }
__device__ __forceinline__ float bf16hi(uint v) { return __uint_as_float(v & 0xffff0000u); }
__device__ __forceinline__ uint packbf16(float a, float b) {
    return (uint)__bfloat16_as_ushort(__float2bfloat16(a)) |
           ((uint)__bfloat16_as_ushort(__float2bfloat16(b)) << 16);
}
__device__ __forceinline__ short f2bf(float v) {
    return (short)__bfloat16_as_ushort(__float2bfloat16(v));
}
__device__ __forceinline__ float bf16tof(short v) {
    return __uint_as_float(((uint)(ushort)v) << 16);
}

// ---------------- CSR scan/scatter ----------------

__global__ void scan1_kernel(const int* __restrict__ deg, int* __restrict__ rs,
                             int* __restrict__ bsum) {
    __shared__ int sh[256];
    int tid = threadIdx.x;
    int i = blockIdx.x * 256 + tid;
    int v = (i < NN) ? deg[i] : 0;
    sh[tid] = v;
    __syncthreads();
    for (int off = 1; off < 256; off <<= 1) {
        int t = (tid >= off) ? sh[tid - off] : 0;
        __syncthreads();
        sh[tid] += t;
        __syncthreads();
    }
    if (i < NN) rs[i] = sh[tid] - v;  // exclusive
    if (tid == 255) bsum[blockIdx.x] = sh[255];
}

__global__ void scan2_kernel(const int* __restrict__ bsum, int* __restrict__ bsumx) {
    __shared__ int sh[256];
    int tid = threadIdx.x;
    int v = (tid < NB1) ? bsum[tid] : 0;
    sh[tid] = v;
    __syncthreads();
    for (int off = 1; off < 256; off <<= 1) {
        int t = (tid >= off) ? sh[tid - off] : 0;
        __syncthreads();
        sh[tid] += t;
        __syncthreads();
    }
    if (tid < NB1) bsumx[tid] = sh[tid] - v;
}

__global__ void scan3_kernel(int* __restrict__ rs, const int* __restrict__ bsumx) {
    int i = blockIdx.x * 256 + threadIdx.x;
    if (i < NN) rs[i] += bsumx[i >> 8];
}

__global__ void scatter_kernel(const int* __restrict__ ei, const int* __restrict__ rs,
                               int* __restrict__ cnt2, int* __restrict__ csr) {
    int e = blockIdx.x * 256 + threadIdx.x;
    if (e >= NE) return;
    int s = ei[e], d = ei[NE + e];
    int pos = rs[d] + atomicAdd(&cnt2[d], 1);
    csr[pos] = s;
}

// ---------------- fused cast + degree + weight-prep (independent streams) ----------------

__global__ void fused_prep_kernel(const float* __restrict__ x, short* __restrict__ xb,
                                  const int* __restrict__ ei, int* __restrict__ deg,
                                  const float* __restrict__ W0, const float* __restrict__ aS0,
                                  const float* __restrict__ aD0, const float* __restrict__ W1,
                                  const float* __restrict__ aS1, const float* __restrict__ aD1,
                                  short* __restrict__ Bp0, short* __restrict__ Bp1,
                                  short* __restrict__ wA1b) {
    int i = blockIdx.x * 256 + threadIdx.x;
    if (i < CASTN) {
        float4 v = ((const float4*)x)[i];
        short4 r;
        r.x = f2bf(v.x); r.y = f2bf(v.y); r.z = f2bf(v.z); r.w = f2bf(v.w);
        ((short4*)xb)[i] = r;
        return;
    }
    int e = i - CASTN;
    if (e < NE) {
        atomicAdd(&deg[ei[NE + e]], 1);
        return;
    }
    int tid = e - NE;
    if (tid < PK0) {
        int j = tid & 7, l = (tid >> 3) & 63, ks = (tid >> 9) & 7, t = tid >> 12;
        int k = ks * 32 + (l >> 4) * 8 + j;
        float v;
        if (t < 8) {
            int c = t * 16 + (l & 15);
            v = W0[(size_t)k * 128 + c];
        } else {  // alpha tile: col jj<8 -> as0 head jj; jj>=8 -> ad0 head jj-8
            int jj = l & 15;
            int hh = jj & 7;
            const float* av = (jj < 8) ? aS0 : aD0;
            float sum = 0.f;
            for (int dd = 0; dd < D0; ++dd)
                sum += W0[(size_t)k * 128 + hh * D0 + dd] * av[hh * D0 + dd];
            v = sum;
        }
        Bp0[tid] = f2bf(v);
    } else if (tid < PK0 + PK1) {
        int t2 = tid - PK0;
        int j = t2 & 7, l = (t2 >> 3) & 63, ks = (t2 >> 9) & 31, t = t2 >> 14;
        int kk = ks * 32 + (l >> 4) * 8 + j;
        int c = t * 16 + (l & 15);
        Bp1[t2] = f2bf(W1[(size_t)(kk & 127) * 512 + (kk >> 7) * 64 + c] * 0.125f);
    } else if (tid < PREPN) {
        // wA1b packed MFMA B-frag: K=128 (x1 dims), N=16: cols 0-7 = wS head c,
        // cols 8-15 = wD head c-8; w[h,k] = sum_d W1[k, h*64+d] * a1[h,d]
        int t3 = tid - PK0 - PK1;
        int j = t3 & 7, l = (t3 >> 3) & 63, ks = t3 >> 9;  // ks 0..3
        int k = ks * 32 + (l >> 4) * 8 + j;
        int c = l & 15;
        int h = c & 7;
        const float* av = (c < 8) ? aS1 : aD1;
        float sum = 0.f;
        for (int d2 = 0; d2 < NCLS; ++d2)
            sum += W1[(size_t)k * 512 + h * NCLS + d2] * av[h * NCLS + d2];
        wA1b[t3] = f2bf(sum);
    }
}

// ---------------- MFMA GEMMs ----------------

// h0b = xb @ W0 (bf16 out) AND as0/ad0 = xb @ W0A (alpha tile), fused.
__global__ __launch_bounds__(256) void gemm0_mfma(const short* __restrict__ xb,
                                                  const short* __restrict__ Bp,
                                                  ushort* __restrict__ h0b,
                                                  float* __restrict__ as0,
                                                  float* __restrict__ ad0) {
    int lane = threadIdx.x & 63, wave = threadIdx.x >> 6;
    int rg = wave >> 1, cg = wave & 1;
    int q = lane >> 4, c16 = lane & 15;
    int row0 = blockIdx.x * 32 + rg * 16;
    int arow = row0 + c16;
    if (arow > NN - 1) arow = NN - 1;
    const short* ap = xb + (size_t)arow * NF + q * 8;
    floatx4 acc[5] = {};
#pragma unroll
    for (int ks = 0; ks < 8; ++ks) {
        short8 af = *(const short8*)(ap + ks * 32);
#pragma unroll
        for (int tt = 0; tt < 4; ++tt) {
            int t = cg * 4 + tt;
            short8 bf = *(const short8*)(Bp + (((size_t)t * 8 + ks) * 64 + lane) * 8);
            acc[tt] = __builtin_amdgcn_mfma_f32_16x16x32_bf16(af, bf, acc[tt], 0, 0, 0);
        }
        if (cg) {  // wave-uniform: alpha tile t=8
            short8 bf = *(const short8*)(Bp + (((size_t)8 * 8 + ks) * 64 + lane) * 8);
            acc[4] = __builtin_amdgcn_mfma_f32_16x16x32_bf16(af, bf, acc[4], 0, 0, 0);
        }
    }
#pragma unroll
    for (int r = 0; r < 4; ++r) {
        int grow = row0 + q * 4 + r;
        if (grow >= NN) continue;
#pragma unroll
        for (int tt = 0; tt < 4; ++tt)
            h0b[(size_t)grow * NHID + cg * 64 + tt * 16 + c16] =
                (ushort)f2bf(acc[tt][r]);
        if (cg) {
            float v = acc[4][r];
            if (c16 < 8) as0[grow * 8 + c16] = v;
            else         ad0[grow * 8 + (c16 - 8)] = v;
        }
    }
}

// as1/ad1 = x1b @ wA1b  (tiny MFMA: 16 rows/wave, K=128, N=16)
__global__ __launch_bounds__(256) void alpha1_mfma(const ushort* __restrict__ x1b,
                                                   const short* __restrict__ wA1b,
                                                   float* __restrict__ as1,
                                                   float* __restrict__ ad1) {
    int lane = threadIdx.x & 63, wave = threadIdx.x >> 6;
    int q = lane >> 4, c16 = lane & 15;
    int row0 = blockIdx.x * 64 + wave * 16;
    int arow = row0 + c16;
    if (arow > NN - 1) arow = NN - 1;
    const short* ap = (const short*)x1b + (size_t)arow * NHID + q * 8;
    floatx4 acc = {};
#pragma unroll
    for (int ks = 0; ks < 4; ++ks) {
        short8 af = *(const short8*)(ap + ks * 32);
        short8 bf = *(const short8*)(wA1b + (((size_t)ks) * 64 + lane) * 8);
        acc = __builtin_amdgcn_mfma_f32_16x16x32_bf16(af, bf, acc, 0, 0, 0);
    }
#pragma unroll
    for (int r = 0; r < 4; ++r) {
        int grow = row0 + q * 4 + r;
        if (grow >= NN) continue;
        float v = acc[r];
        if (c16 < 8) as1[grow * 8 + c16] = v;
        else         ad1[grow * 8 + (c16 - 8)] = v;
    }
}

// ---------------- fused edge kernels ----------------
// softmax without max subtraction (shift-invariant; logits O(+-6)).

// Layer 0: one wave per dst, 16-deep chunks (two 8-edge alpha groups, all 16
// gathers issued before first use -> 16-deep MLP, one iteration for deg<=16).
__global__ __launch_bounds__(256) void fused_edge0(
    const int* __restrict__ rs, const int* __restrict__ deg, const int* __restrict__ csr,
    const ushort* __restrict__ h0b, const float* __restrict__ as0, const float* __restrict__ ad0,
    const float* __restrict__ b0, ushort* __restrict__ x1b) {
    int d = (blockIdx.x * 256 + threadIdx.x) >> 6;
    int lane = threadIdx.x & 63;
    if (d >= NN) return;
    int row = rs[d], dg = deg[d];
    int hl = lane & 7, g = lane >> 3;
    int hp = lane >> 3;  // head owning this lane's dim pair
    float adv = ad0[d * 8 + hl];
    float den = 0.f;
    float2 acc = {0.f, 0.f};
    for (int base = 0; base < dg; base += 16) {
        int i0 = base + g, i1 = base + 8 + g;
        int s0 = (i0 < dg) ? csr[row + i0] : 0;
        int s1 = (i1 < dg) ? csr[row + i1] : 0;
        float ev0 = as0[s0 * 8 + hl] + adv;
        ev0 = ev0 > 0.f ? ev0 : 0.2f * ev0;
        float p0 = (i0 < dg) ? __expf(ev0) : 0.f;
        float ev1 = as0[s1 * 8 + hl] + adv;
        ev1 = ev1 > 0.f ? ev1 : 0.2f * ev1;
        float p1 = (i1 < dg) ? __expf(ev1) : 0.f;
        den += p0 + p1;
        uint vbuf[16];
#pragma unroll
        for (int g2 = 0; g2 < 8; ++g2) {
            int sg = __builtin_amdgcn_readlane(s0, g2 * 8);  // scalar base
            vbuf[g2] = *(const uint*)(h0b + (size_t)sg * NHID + 2 * lane);
        }
#pragma unroll
        for (int g2 = 0; g2 < 8; ++g2) {
            int sg = __builtin_amdgcn_readlane(s1, g2 * 8);
            vbuf[8 + g2] = *(const uint*)(h0b + (size_t)sg * NHID + 2 * lane);
        }
#pragma unroll
        for (int g2 = 0; g2 < 8; ++g2) {
            float ph = __shfl(p0, g2 * 8 + hp);  // hp per-lane -> bpermute
            acc.x += bf16lo(vbuf[g2]) * ph;
            acc.y += bf16hi(vbuf[g2]) * ph;
        }
#pragma unroll
        for (int g2 = 0; g2 < 8; ++g2) {
            float ph = __shfl(p1, g2 * 8 + hp);
            acc.x += bf16lo(vbuf[8 + g2]) * ph;
            acc.y += bf16hi(vbuf[8 + g2]) * ph;
        }
    }
    den += __shfl_xor(den, 8);
    den += __shfl_xor(den, 16);
    den += __shfl_xor(den, 32);
    float dh = __shfl(den, hp);
    float inv = 1.f / (dh + 1e-16f);
    float2 bb = ((const float2*)b0)[lane];
    float o0 = acc.x * inv + bb.x;
    float o1 = acc.y * inv + bb.y;
    o0 = o0 > 0.f ? o0 : expf(o0) - 1.f;
    o1 = o1 > 0.f ? o1 : expf(o1) - 1.f;
    *(uint*)(x1b + (size_t)d * NHID + 2 * lane) = packbf16(o0, o1);
}

// Layer 1: MFMA aggregation + BLOCK-COOPERATIVE output GEMM + log_softmax.
// Block = 4 waves = 8 dsts (wave w owns dA=2*(blk*4+w), dB=dA+1). Grid 6250
// exact (50000 = 6250*8): no early returns -> barriers legal. (r4 geometry —
// r5's 512-thr/16-dst variant regressed: occupancy 46->38%, 16-dst straggler.)
// Stage 1 (per wave): one mfma per 16-col tile;
//   A[m,k] = alpha_bf16[dst=(m<8?A:B), head=m&7], zero when (m<8)!=(k<16)
//   B[k,n] = x1b[src[edge k], n] gathered in B-frag layout (2B loads = transpose)
// aggN (bf16, identical rounding to old AGG path) -> aggNsh[8][1036]
// (stride 518 dw = 6 mod 32 banks: 16 A-frag rows (c16&7 dup) start on
// distinct banks).
// Stage 2 (cooperative, t-split): wave w computes FINAL C cols [16w,16w+16)
// over all 32 k-steps (two interleaved acc chains for ILP). No partial-C
// reduce: Csh is 2 KB, epilogue reads it directly.
// Per block: 128 MFMA cells, 131 KB Bp1 (full set read once — same as r4).
__global__ __launch_bounds__(256) void fused_edge1(
    const int* __restrict__ rs, const int* __restrict__ deg, const int* __restrict__ csr,
    const ushort* __restrict__ x1b, const float* __restrict__ as1, const float* __restrict__ ad1,
    const short* __restrict__ Bp1, const float* __restrict__ b1, float* __restrict__ out) {
    __shared__ ushort aggNsh[8][1036];  // 16.6 KB, stride 6 mod 32 banks
    __shared__ float Csh[8][64];        // 2 KB final C
    int wave = threadIdx.x >> 6;
    int lane = threadIdx.x & 63;
    int gw = blockIdx.x * 4 + wave;
    int dA = 2 * gw;
    int dB = dA + 1;
    int q = lane >> 4, c16 = lane & 15, h7 = lane & 7;
    int d_l = (lane >= 32) ? dB : dA;
    int row_l = rs[d_l], dg_l = deg[d_l];
    // A-frag validity: (m<8) == (k<16)  <=>  ((lane&8)==0) == (lane<32)
    bool V = ((lane & 8) == 0) == (lane < 32);
    float adv = ad1[d_l * 8 + h7];
    int dgA = __shfl(dg_l, 0);
    int dgB = __shfl(dg_l, 32);
    int dgmax = dgA > dgB ? dgA : dgB;
    float den = 0.f;
    floatx4 acc[8] = {};
    for (int base = 0; base < dgmax; base += 16) {
        short8 af;
        int sarr[8];
#pragma unroll
        for (int j = 0; j < 8; ++j) {
            int idx = base + (q & 1) * 8 + j;  // edge slot within this lane's dst
            int s = 0;
            if (idx < dg_l) s = csr[row_l + idx];
            sarr[j] = s;
            float ev = as1[s * 8 + h7] + adv;
            ev = ev > 0.f ? ev : 0.2f * ev;
            float p = __expf(ev);
            p = (idx < dg_l && V) ? p : 0.f;
            short pb = f2bf(p);
            af[j] = pb;
            den += bf16tof(pb);  // den over bf16-rounded alpha (matches MFMA)
        }
#pragma unroll
        for (int t = 0; t < 8; ++t) {
            short8 bv;
#pragma unroll
            for (int j = 0; j < 8; ++j)
                bv[j] = (short)x1b[(size_t)sarr[j] * NHID + t * 16 + c16];
            acc[t] = __builtin_amdgcn_mfma_f32_16x16x32_bf16(af, bv, acc[t], 0, 0, 0);
        }
    }
    // den per (dst, head): valid partials live at lanes {h, h+16} of each half
    den += __shfl_xor(den, 8);
    den += __shfl_xor(den, 16);
    // normalize + stage to LDS: C[m = q*4+r, n = t*16+c16]
    int hbase = (q & 1) * 4;
    int lrow = wave * 2 + (lane >> 5);  // local dst row 0..7 = global dst blk*8+lrow
#pragma unroll
    for (int r = 0; r < 4; ++r) {
        int hh = hbase + r;
        float dh = __shfl(den, (lane & 32) + hh);
        float inv = 1.f / (dh + 1e-16f);
#pragma unroll
        for (int t = 0; t < 8; ++t)
            aggNsh[lrow][hh * 128 + t * 16 + c16] = (ushort)f2bf(acc[t][r] * inv);
    }
    __syncthreads();
    // ---- stage 2: wave w -> t=w (final cols 16w..16w+15), all ks 0..31 ----
    {
        int t = wave;
        const short* abase = (const short*)&aggNsh[c16 & 7][0] + q * 8;
        floatx4 acc2a = {}, acc2b = {};
#pragma unroll
        for (int kk = 0; kk < 16; ++kk) {
            short8 afa = *(const short8*)(abase + kk * 32);
            short8 bfa = *(const short8*)(Bp1 + (((size_t)t * 32 + kk) * 64 + lane) * 8);
            acc2a = __builtin_amdgcn_mfma_f32_16x16x32_bf16(afa, bfa, acc2a, 0, 0, 0);
            short8 afb = *(const short8*)(abase + (kk + 16) * 32);
            short8 bfb = *(const short8*)(Bp1 + (((size_t)t * 32 + kk + 16) * 64 + lane) * 8);
            acc2b = __builtin_amdgcn_mfma_f32_16x16x32_bf16(afb, bfb, acc2b, 0, 0, 0);
        }
        if (q < 2) {  // rows m = q*4+r in 0..7 are the block's dsts
#pragma unroll
            for (int r = 0; r < 4; ++r)
                Csh[q * 4 + r][t * 16 + c16] = acc2a[r] + acc2b[r];
        }
    }
    __syncthreads();
    // ---- epilogue: wave w finishes its own dsts (local rows 2w, 2w+1) ----
    float z0 = Csh[wave * 2][lane];
    float z1 = Csh[wave * 2 + 1][lane];
    float bb = b1[lane];
    z0 += bb;
    z1 += bb;
    float mx0 = z0, mx1 = z1;
#pragma unroll
    for (int x = 1; x < 64; x <<= 1) {
        mx0 = fmaxf(mx0, __shfl_xor(mx0, x));
        mx1 = fmaxf(mx1, __shfl_xor(mx1, x));
    }
    float s0 = expf(z0 - mx0), s1 = expf(z1 - mx1);
#pragma unroll
    for (int x = 1; x < 64; x <<= 1) {
        s0 += __shfl_xor(s0, x);
        s1 += __shfl_xor(s1, x);
    }
    float lse0 = mx0 + logf(s0);
    float lse1 = mx1 + logf(s1);
    out[(size_t)dA * NCLS + lane] = z0 - lse0;
    out[(size_t)dB * NCLS + lane] = z1 - lse1;
}

// ---------------- launch ----------------

extern "C" void kernel_launch(void* const* d_in, const int* in_sizes, int n_in,
                              void* d_out, int out_size, void* d_ws, size_t ws_size,
                              hipStream_t stream) {
    const float* x   = (const float*)d_in[0];
    const int*   ei  = (const int*)d_in[1];
    const float* W0  = (const float*)d_in[2];
    const float* aS0 = (const float*)d_in[3];
    const float* aD0 = (const float*)d_in[4];
    const float* b0  = (const float*)d_in[5];
    const float* W1  = (const float*)d_in[6];
    const float* aS1 = (const float*)d_in[7];
    const float* aD1 = (const float*)d_in[8];
    const float* b1  = (const float*)d_in[9];
    float* out = (float*)d_out;

    char* ws = (char*)d_ws;
    ushort* x1b = (ushort*)ws; ws += (size_t)NN * NHID * 2;           // 12.8 MB
    ushort* h0b = (ushort*)ws; ws += (size_t)NN * NHID * 2;           // 12.8 MB
    short* xb   = (short*)ws; ws += (size_t)NN * NF * 2;              // 25.6 MB
    float* as0  = (float*)ws; ws += (size_t)NN * HEADS * 4;
    float* ad0  = (float*)ws; ws += (size_t)NN * HEADS * 4;
    float* as1  = (float*)ws; ws += (size_t)NN * HEADS * 4;
    float* ad1  = (float*)ws; ws += (size_t)NN * HEADS * 4;
    short* Bp0  = (short*)ws; ws += (size_t)PK0 * 2;
    short* Bp1  = (short*)ws; ws += (size_t)PK1 * 2;
    short* wA1b = (short*)ws; ws += (size_t)PKA * 2;
    int* deg    = (int*)ws; ws += (size_t)NN * 4;
    int* cnt2   = (int*)ws; ws += (size_t)NN * 4;                     // adjacent to deg
    int* rs     = (int*)ws; ws += (size_t)NN * 4;
    int* bsum   = (int*)ws; ws += 256 * 4;
    int* bsumx  = (int*)ws; ws += 256 * 4;
    int* csr    = (int*)ws; ws += (size_t)NE * 4;                     // 2.4 MB

    const int FUSEDN = CASTN + NE + PREPN;

    // ---- zero deg + cnt2, then fused cast/degree/weight-prep ----
    hipMemsetAsync(deg, 0, (size_t)2 * NN * 4, stream);
    fused_prep_kernel<<<(FUSEDN + 255) / 256, 256, 0, stream>>>(
        x, xb, ei, deg, W0, aS0, aD0, W1, aS1, aD1, Bp0, Bp1, wA1b);

    // ---- CSR scan + scatter ----
    scan1_kernel<<<NB1, 256, 0, stream>>>(deg, rs, bsum);
    scan2_kernel<<<1, 256, 0, stream>>>(bsum, bsumx);
    scan3_kernel<<<NB1, 256, 0, stream>>>(rs, bsumx);
    scatter_kernel<<<(NE + 255) / 256, 256, 0, stream>>>(ei, rs, cnt2, csr);

    // ---- layer 0 ----
    gemm0_mfma<<<(NN + 31) / 32, 256, 0, stream>>>(xb, Bp0, h0b, as0, ad0);
    fused_edge0<<<(NN + 3) / 4, 256, 0, stream>>>(rs, deg, csr, h0b, as0, ad0, b0, x1b);

    // ---- layer 1 (aggregation + cooperative output GEMM + log_softmax fused) ----
    alpha1_mfma<<<(NN + 63) / 64, 256, 0, stream>>>(x1b, wA1b, as1, ad1);
    fused_edge1<<<NN / 8, 256, 0, stream>>>(rs, deg, csr, x1b, as1, ad1, Bp1, b1, out);
}

// Round 7
// 310.825 us; speedup vs baseline: 1.1323x; 1.1323x over previous
//
#include <hip/hip_runtime.h>
#include <hip/hip_bf16.h>
#include <math.h>

#define NN 50000
#define NE 600000
#define NF 256
#define NHID 128
#define HEADS 8
#define D0 16
#define NCLS 64
#define NB1 196  // (NN+255)/256

#define PK0 (9 * 8 * 64 * 8)   // Bp0: 8 col-tiles of W0 + 1 alpha tile (W0A)
#define PK1 (4 * 32 * 64 * 8)  // Bp1
#define PKA (4 * 64 * 8)       // wA1b: K=128, N=16 (cols 0-7 wS heads, 8-15 wD)
#define CASTN (NN * NF / 4)    // 3.2M float4 groups
#define PREPN (PK0 + PK1 + PKA)

typedef __attribute__((ext_vector_type(8))) short short8;
typedef __attribute__((ext_vector_type(4))) float floatx4;

__device__ __forceinline__ float bf16lo(uint v) { return __uint_as_float((v & 0xffffu) << 16); }
__device__ __forceinline__ float bf16hi(uint v) { return __uint_as_float(v & 0xffff0000u); }
__device__ __forceinline__ uint packbf16(float a, float b) {
    return (uint)__bfloat16_as_ushort(__float2bfloat16(a)) |
           ((uint)__bfloat16_as_ushort(__float2bfloat16(b)) << 16);
}
__device__ __forceinline__ short f2bf(float v) {
    return (short)__bfloat16_as_ushort(__float2bfloat16(v));
}
__device__ __forceinline__ float bf16tof(short v) {
    return __uint_as_float(((uint)(ushort)v) << 16);
}

// ---------------- CSR scan/scatter ----------------

__global__ void scan1_kernel(const int* __restrict__ deg, int* __restrict__ rs,
                             int* __restrict__ bsum) {
    __shared__ int sh[256];
    int tid = threadIdx.x;
    int i = blockIdx.x * 256 + tid;
    int v = (i < NN) ? deg[i] : 0;
    sh[tid] = v;
    __syncthreads();
    for (int off = 1; off < 256; off <<= 1) {
        int t = (tid >= off) ? sh[tid - off] : 0;
        __syncthreads();
        sh[tid] += t;
        __syncthreads();
    }
    if (i < NN) rs[i] = sh[tid] - v;  // exclusive
    if (tid == 255) bsum[blockIdx.x] = sh[255];
}

__global__ void scan2_kernel(const int* __restrict__ bsum, int* __restrict__ bsumx) {
    __shared__ int sh[256];
    int tid = threadIdx.x;
    int v = (tid < NB1) ? bsum[tid] : 0;
    sh[tid] = v;
    __syncthreads();
    for (int off = 1; off < 256; off <<= 1) {
        int t = (tid >= off) ? sh[tid - off] : 0;
        __syncthreads();
        sh[tid] += t;
        __syncthreads();
    }
    if (tid < NB1) bsumx[tid] = sh[tid] - v;
}

__global__ void scan3_kernel(int* __restrict__ rs, const int* __restrict__ bsumx) {
    int i = blockIdx.x * 256 + threadIdx.x;
    if (i < NN) rs[i] += bsumx[i >> 8];
}

__global__ void scatter_kernel(const int* __restrict__ ei, const int* __restrict__ rs,
                               int* __restrict__ cnt2, int* __restrict__ csr) {
    int e = blockIdx.x * 256 + threadIdx.x;
    if (e >= NE) return;
    int s = ei[e], d = ei[NE + e];
    int pos = rs[d] + atomicAdd(&cnt2[d], 1);
    csr[pos] = s;
}

// ---------------- fused cast + degree + weight-prep (independent streams) ----------------

__global__ void fused_prep_kernel(const float* __restrict__ x, short* __restrict__ xb,
                                  const int* __restrict__ ei, int* __restrict__ deg,
                                  const float* __restrict__ W0, const float* __restrict__ aS0,
                                  const float* __restrict__ aD0, const float* __restrict__ W1,
                                  const float* __restrict__ aS1, const float* __restrict__ aD1,
                                  short* __restrict__ Bp0, short* __restrict__ Bp1,
                                  short* __restrict__ wA1b) {
    int i = blockIdx.x * 256 + threadIdx.x;
    if (i < CASTN) {
        float4 v = ((const float4*)x)[i];
        short4 r;
        r.x = f2bf(v.x); r.y = f2bf(v.y); r.z = f2bf(v.z); r.w = f2bf(v.w);
        ((short4*)xb)[i] = r;
        return;
    }
    int e = i - CASTN;
    if (e < NE) {
        atomicAdd(&deg[ei[NE + e]], 1);
        return;
    }
    int tid = e - NE;
    if (tid < PK0) {
        int j = tid & 7, l = (tid >> 3) & 63, ks = (tid >> 9) & 7, t = tid >> 12;
        int k = ks * 32 + (l >> 4) * 8 + j;
        float v;
        if (t < 8) {
            int c = t * 16 + (l & 15);
            v = W0[(size_t)k * 128 + c];
        } else {  // alpha tile: col jj<8 -> as0 head jj; jj>=8 -> ad0 head jj-8
            int jj = l & 15;
            int hh = jj & 7;
            const float* av = (jj < 8) ? aS0 : aD0;
            float sum = 0.f;
            for (int dd = 0; dd < D0; ++dd)
                sum += W0[(size_t)k * 128 + hh * D0 + dd] * av[hh * D0 + dd];
            v = sum;
        }
        Bp0[tid] = f2bf(v);
    } else if (tid < PK0 + PK1) {
        int t2 = tid - PK0;
        int j = t2 & 7, l = (t2 >> 3) & 63, ks = (t2 >> 9) & 31, t = t2 >> 14;
        int kk = ks * 32 + (l >> 4) * 8 + j;
        int c = t * 16 + (l & 15);
        Bp1[t2] = f2bf(W1[(size_t)(kk & 127) * 512 + (kk >> 7) * 64 + c] * 0.125f);
    } else if (tid < PREPN) {
        // wA1b packed MFMA B-frag: K=128 (x1 dims), N=16: cols 0-7 = wS head c,
        // cols 8-15 = wD head c-8; w[h,k] = sum_d W1[k, h*64+d] * a1[h,d]
        int t3 = tid - PK0 - PK1;
        int j = t3 & 7, l = (t3 >> 3) & 63, ks = t3 >> 9;  // ks 0..3
        int k = ks * 32 + (l >> 4) * 8 + j;
        int c = l & 15;
        int h = c & 7;
        const float* av = (c < 8) ? aS1 : aD1;
        float sum = 0.f;
        for (int d2 = 0; d2 < NCLS; ++d2)
            sum += W1[(size_t)k * 512 + h * NCLS + d2] * av[h * NCLS + d2];
        wA1b[t3] = f2bf(sum);
    }
}

// ---------------- MFMA GEMMs ----------------

// h0b = xb @ W0 (bf16 out) AND as0/ad0 = xb @ W0A (alpha tile), fused.
__global__ __launch_bounds__(256) void gemm0_mfma(const short* __restrict__ xb,
                                                  const short* __restrict__ Bp,
                                                  ushort* __restrict__ h0b,
                                                  float* __restrict__ as0,
                                                  float* __restrict__ ad0) {
    int lane = threadIdx.x & 63, wave = threadIdx.x >> 6;
    int rg = wave >> 1, cg = wave & 1;
    int q = lane >> 4, c16 = lane & 15;
    int row0 = blockIdx.x * 32 + rg * 16;
    int arow = row0 + c16;
    if (arow > NN - 1) arow = NN - 1;
    const short* ap = xb + (size_t)arow * NF + q * 8;
    floatx4 acc[5] = {};
#pragma unroll
    for (int ks = 0; ks < 8; ++ks) {
        short8 af = *(const short8*)(ap + ks * 32);
#pragma unroll
        for (int tt = 0; tt < 4; ++tt) {
            int t = cg * 4 + tt;
            short8 bf = *(const short8*)(Bp + (((size_t)t * 8 + ks) * 64 + lane) * 8);
            acc[tt] = __builtin_amdgcn_mfma_f32_16x16x32_bf16(af, bf, acc[tt], 0, 0, 0);
        }
        if (cg) {  // wave-uniform: alpha tile t=8
            short8 bf = *(const short8*)(Bp + (((size_t)8 * 8 + ks) * 64 + lane) * 8);
            acc[4] = __builtin_amdgcn_mfma_f32_16x16x32_bf16(af, bf, acc[4], 0, 0, 0);
        }
    }
#pragma unroll
    for (int r = 0; r < 4; ++r) {
        int grow = row0 + q * 4 + r;
        if (grow >= NN) continue;
#pragma unroll
        for (int tt = 0; tt < 4; ++tt)
            h0b[(size_t)grow * NHID + cg * 64 + tt * 16 + c16] =
                (ushort)f2bf(acc[tt][r]);
        if (cg) {
            float v = acc[4][r];
            if (c16 < 8) as0[grow * 8 + c16] = v;
            else         ad0[grow * 8 + (c16 - 8)] = v;
        }
    }
}

// as1/ad1 = x1b @ wA1b  (tiny MFMA: 16 rows/wave, K=128, N=16)
__global__ __launch_bounds__(256) void alpha1_mfma(const ushort* __restrict__ x1b,
                                                   const short* __restrict__ wA1b,
                                                   float* __restrict__ as1,
                                                   float* __restrict__ ad1) {
    int lane = threadIdx.x & 63, wave = threadIdx.x >> 6;
    int q = lane >> 4, c16 = lane & 15;
    int row0 = blockIdx.x * 64 + wave * 16;
    int arow = row0 + c16;
    if (arow > NN - 1) arow = NN - 1;
    const short* ap = (const short*)x1b + (size_t)arow * NHID + q * 8;
    floatx4 acc = {};
#pragma unroll
    for (int ks = 0; ks < 4; ++ks) {
        short8 af = *(const short8*)(ap + ks * 32);
        short8 bf = *(const short8*)(wA1b + (((size_t)ks) * 64 + lane) * 8);
        acc = __builtin_amdgcn_mfma_f32_16x16x32_bf16(af, bf, acc, 0, 0, 0);
    }
#pragma unroll
    for (int r = 0; r < 4; ++r) {
        int grow = row0 + q * 4 + r;
        if (grow >= NN) continue;
        float v = acc[r];
        if (c16 < 8) as1[grow * 8 + c16] = v;
        else         ad1[grow * 8 + (c16 - 8)] = v;
    }
}

// ---------------- fused edge kernels ----------------
// softmax without max subtraction (shift-invariant; logits O(+-6)).

// Layer 0: one wave per dst, 16-deep chunks (two 8-edge alpha groups, all 16
// gathers issued before first use -> 16-deep MLP, one iteration for deg<=16).
__global__ __launch_bounds__(256) void fused_edge0(
    const int* __restrict__ rs, const int* __restrict__ deg, const int* __restrict__ csr,
    const ushort* __restrict__ h0b, const float* __restrict__ as0, const float* __restrict__ ad0,
    const float* __restrict__ b0, ushort* __restrict__ x1b) {
    int d = (blockIdx.x * 256 + threadIdx.x) >> 6;
    int lane = threadIdx.x & 63;
    if (d >= NN) return;
    int row = rs[d], dg = deg[d];
    int hl = lane & 7, g = lane >> 3;
    int hp = lane >> 3;  // head owning this lane's dim pair
    float adv = ad0[d * 8 + hl];
    float den = 0.f;
    float2 acc = {0.f, 0.f};
    for (int base = 0; base < dg; base += 16) {
        int i0 = base + g, i1 = base + 8 + g;
        int s0 = (i0 < dg) ? csr[row + i0] : 0;
        int s1 = (i1 < dg) ? csr[row + i1] : 0;
        float ev0 = as0[s0 * 8 + hl] + adv;
        ev0 = ev0 > 0.f ? ev0 : 0.2f * ev0;
        float p0 = (i0 < dg) ? __expf(ev0) : 0.f;
        float ev1 = as0[s1 * 8 + hl] + adv;
        ev1 = ev1 > 0.f ? ev1 : 0.2f * ev1;
        float p1 = (i1 < dg) ? __expf(ev1) : 0.f;
        den += p0 + p1;
        uint vbuf[16];
#pragma unroll
    for (int g2 = 0; g2 < 8; ++g2) {
            int sg = __builtin_amdgcn_readlane(s0, g2 * 8);  // scalar base
            vbuf[g2] = *(const uint*)(h0b + (size_t)sg * NHID + 2 * lane);
        }
#pragma unroll
        for (int g2 = 0; g2 < 8; ++g2) {
            int sg = __builtin_amdgcn_readlane(s1, g2 * 8);
            vbuf[8 + g2] = *(const uint*)(h0b + (size_t)sg * NHID + 2 * lane);
        }
#pragma unroll
        for (int g2 = 0; g2 < 8; ++g2) {
            float ph = __shfl(p0, g2 * 8 + hp);  // hp per-lane -> bpermute
            acc.x += bf16lo(vbuf[g2]) * ph;
            acc.y += bf16hi(vbuf[g2]) * ph;
        }
#pragma unroll
        for (int g2 = 0; g2 < 8; ++g2) {
            float ph = __shfl(p1, g2 * 8 + hp);
            acc.x += bf16lo(vbuf[8 + g2]) * ph;
            acc.y += bf16hi(vbuf[8 + g2]) * ph;
        }
    }
    den += __shfl_xor(den, 8);
    den += __shfl_xor(den, 16);
    den += __shfl_xor(den, 32);
    float dh = __shfl(den, hp);
    float inv = 1.f / (dh + 1e-16f);
    float2 bb = ((const float2*)b0)[lane];
    float o0 = acc.x * inv + bb.x;
    float o1 = acc.y * inv + bb.y;
    o0 = o0 > 0.f ? o0 : expf(o0) - 1.f;
    o1 = o1 > 0.f ? o1 : expf(o1) - 1.f;
    *(uint*)(x1b + (size_t)d * NHID + 2 * lane) = packbf16(o0, o1);
}

// Layer 1: MFMA aggregation + BLOCK-COOPERATIVE output GEMM + log_softmax.
// EXACT r4 structure (proven 88 us) — only the aggNsh padding differs
// (1032 -> 1036: stride 518 dw = 6 mod 32 banks, fewer stage-2 conflicts).
// Block = 4 waves = 8 dsts (wave w owns dA=2*(blk*4+w), dB=dA+1). Grid 6250
// exact: no early returns -> barriers legal.
// Stage 1 (per wave): one mfma per 16-col tile;
//   A[m,k] = alpha_bf16[dst=(m<8?A:B), head=m&7], zero when (m<8)!=(k<16)
//   B[k,n] = x1b[src[edge k], n] gathered in B-frag layout (2B loads = transpose)
// Stage 2 (cooperative, ks-split): wave w does ks = w*8..w*8+7, all 4 t-tiles
// (af2 loaded once per ks, reused 4x; acc2[4] = 4 independent MFMA chains).
// Partial C staged to Csh[4][8][64], reduced in 64-lane epilogue (lane=class).
__global__ __launch_bounds__(256) void fused_edge1(
    const int* __restrict__ rs, const int* __restrict__ deg, const int* __restrict__ csr,
    const ushort* __restrict__ x1b, const float* __restrict__ as1, const float* __restrict__ ad1,
    const short* __restrict__ Bp1, const float* __restrict__ b1, float* __restrict__ out) {
    __shared__ ushort aggNsh[8][1036];  // 16.6 KB, stride 6 mod 32 banks
    __shared__ float Csh[4][8][64];     // 8 KB partial C
    int wave = threadIdx.x >> 6;
    int lane = threadIdx.x & 63;
    int gw = blockIdx.x * 4 + wave;
    int dA = 2 * gw;
    int dB = dA + 1;
    int q = lane >> 4, c16 = lane & 15, h7 = lane & 7;
    int d_l = (lane >= 32) ? dB : dA;
    int row_l = rs[d_l], dg_l = deg[d_l];
    // A-frag validity: (m<8) == (k<16)  <=>  ((lane&8)==0) == (lane<32)
    bool V = ((lane & 8) == 0) == (lane < 32);
    float adv = ad1[d_l * 8 + h7];
    int dgA = __shfl(dg_l, 0);
    int dgB = __shfl(dg_l, 32);
    int dgmax = dgA > dgB ? dgA : dgB;
    float den = 0.f;
    floatx4 acc[8] = {};
    for (int base = 0; base < dgmax; base += 16) {
        short8 af;
        int sarr[8];
#pragma unroll
        for (int j = 0; j < 8; ++j) {
            int idx = base + (q & 1) * 8 + j;  // edge slot within this lane's dst
            int s = 0;
            if (idx < dg_l) s = csr[row_l + idx];
            sarr[j] = s;
            float ev = as1[s * 8 + h7] + adv;
            ev = ev > 0.f ? ev : 0.2f * ev;
            float p = __expf(ev);
            p = (idx < dg_l && V) ? p : 0.f;
            short pb = f2bf(p);
            af[j] = pb;
            den += bf16tof(pb);  // den over bf16-rounded alpha (matches MFMA)
        }
#pragma unroll
        for (int t = 0; t < 8; ++t) {
            short8 bv;
#pragma unroll
            for (int j = 0; j < 8; ++j)
                bv[j] = (short)x1b[(size_t)sarr[j] * NHID + t * 16 + c16];
            acc[t] = __builtin_amdgcn_mfma_f32_16x16x32_bf16(af, bv, acc[t], 0, 0, 0);
        }
    }
    // den per (dst, head): valid partials live at lanes {h, h+16} of each half
    den += __shfl_xor(den, 8);
    den += __shfl_xor(den, 16);
    // normalize + stage to LDS: C[m = q*4+r, n = t*16+c16]
    int hbase = (q & 1) * 4;
    int lrow = wave * 2 + (lane >> 5);  // local dst row 0..7 = global dst blk*8+lrow
#pragma unroll
    for (int r = 0; r < 4; ++r) {
        int hh = hbase + r;
        float dh = __shfl(den, (lane & 32) + hh);
        float inv = 1.f / (dh + 1e-16f);
#pragma unroll
        for (int t = 0; t < 8; ++t)
            aggNsh[lrow][hh * 128 + t * 16 + c16] = (ushort)f2bf(acc[t][r] * inv);
    }
    __syncthreads();
    // ---- stage 2: cooperative GEMM, wave w covers ks in [w*8, w*8+8) ----
    {
        floatx4 acc2[4] = {};
        const short* abase = (const short*)&aggNsh[c16 & 7][0];
        int ks0 = wave * 8;
#pragma unroll
        for (int kk = 0; kk < 8; ++kk) {
            int ks = ks0 + kk;
            short8 af2 = *(const short8*)(abase + ks * 32 + q * 8);
#pragma unroll
            for (int t = 0; t < 4; ++t) {
                short8 bf = *(const short8*)(Bp1 + (((size_t)t * 32 + ks) * 64 + lane) * 8);
                acc2[t] = __builtin_amdgcn_mfma_f32_16x16x32_bf16(af2, bf, acc2[t], 0, 0, 0);
            }
        }
        if (q < 2) {  // rows m = q*4+r in 0..7 are valid
#pragma unroll
            for (int r = 0; r < 4; ++r)
#pragma unroll
                for (int t = 0; t < 4; ++t)
                    Csh[wave][q * 4 + r][t * 16 + c16] = acc2[t][r];
        }
    }
    __syncthreads();
    // ---- epilogue: wave w finishes its own dsts (local rows 2w, 2w+1) ----
    float z0 = 0.f, z1 = 0.f;
#pragma unroll
    for (int w2 = 0; w2 < 4; ++w2) {
        z0 += Csh[w2][wave * 2][lane];
        z1 += Csh[w2][wave * 2 + 1][lane];
    }
    float bb = b1[lane];
    z0 += bb;
    z1 += bb;
    float mx0 = z0, mx1 = z1;
#pragma unroll
    for (int x = 1; x < 64; x <<= 1) {
        mx0 = fmaxf(mx0, __shfl_xor(mx0, x));
        mx1 = fmaxf(mx1, __shfl_xor(mx1, x));
    }
    float s0 = expf(z0 - mx0), s1 = expf(z1 - mx1);
#pragma unroll
    for (int x = 1; x < 64; x <<= 1) {
        s0 += __shfl_xor(s0, x);
        s1 += __shfl_xor(s1, x);
    }
    float lse0 = mx0 + logf(s0);
    float lse1 = mx1 + logf(s1);
    out[(size_t)dA * NCLS + lane] = z0 - lse0;
    out[(size_t)dB * NCLS + lane] = z1 - lse1;
}

// ---------------- launch ----------------

extern "C" void kernel_launch(void* const* d_in, const int* in_sizes, int n_in,
                              void* d_out, int out_size, void* d_ws, size_t ws_size,
                              hipStream_t stream) {
    const float* x   = (const float*)d_in[0];
    const int*   ei  = (const int*)d_in[1];
    const float* W0  = (const float*)d_in[2];
    const float* aS0 = (const float*)d_in[3];
    const float* aD0 = (const float*)d_in[4];
    const float* b0  = (const float*)d_in[5];
    const float* W1  = (const float*)d_in[6];
    const float* aS1 = (const float*)d_in[7];
    const float* aD1 = (const float*)d_in[8];
    const float* b1  = (const float*)d_in[9];
    float* out = (float*)d_out;

    char* ws = (char*)d_ws;
    ushort* x1b = (ushort*)ws; ws += (size_t)NN * NHID * 2;           // 12.8 MB
    ushort* h0b = (ushort*)ws; ws += (size_t)NN * NHID * 2;           // 12.8 MB
    short* xb   = (short*)ws; ws += (size_t)NN * NF * 2;              // 25.6 MB
    float* as0  = (float*)ws; ws += (size_t)NN * HEADS * 4;
    float* ad0  = (float*)ws; ws += (size_t)NN * HEADS * 4;
    float* as1  = (float*)ws; ws += (size_t)NN * HEADS * 4;
    float* ad1  = (float*)ws; ws += (size_t)NN * HEADS * 4;
    short* Bp0  = (short*)ws; ws += (size_t)PK0 * 2;
    short* Bp1  = (short*)ws; ws += (size_t)PK1 * 2;
    short* wA1b = (short*)ws; ws += (size_t)PKA * 2;
    int* deg    = (int*)ws; ws += (size_t)NN * 4;
    int* cnt2   = (int*)ws; ws += (size_t)NN * 4;                     // adjacent to deg
    int* rs     = (int*)ws; ws += (size_t)NN * 4;
    int* bsum   = (int*)ws; ws += 256 * 4;
    int* bsumx  = (int*)ws; ws += 256 * 4;
    int* csr    = (int*)ws; ws += (size_t)NE * 4;                     // 2.4 MB

    const int FUSEDN = CASTN + NE + PREPN;

    // ---- zero deg + cnt2, then fused cast/degree/weight-prep ----
    hipMemsetAsync(deg, 0, (size_t)2 * NN * 4, stream);
    fused_prep_kernel<<<(FUSEDN + 255) / 256, 256, 0, stream>>>(
        x, xb, ei, deg, W0, aS0, aD0, W1, aS1, aD1, Bp0, Bp1, wA1b);

    // ---- CSR scan + scatter ----
    scan1_kernel<<<NB1, 256, 0, stream>>>(deg, rs, bsum);
    scan2_kernel<<<1, 256, 0, stream>>>(bsum, bsumx);
    scan3_kernel<<<NB1, 256, 0, stream>>>(rs, bsumx);
    scatter_kernel<<<(NE + 255) / 256, 256, 0, stream>>>(ei, rs, cnt2, csr);

    // ---- layer 0 ----
    gemm0_mfma<<<(NN + 31) / 32, 256, 0, stream>>>(xb, Bp0, h0b, as0, ad0);
    fused_edge0<<<(NN + 3) / 4, 256, 0, stream>>>(rs, deg, csr, h0b, as0, ad0, b0, x1b);

    // ---- layer 1 (aggregation + cooperative output GEMM + log_softmax fused) ----
    alpha1_mfma<<<(NN + 63) / 64, 256, 0, stream>>>(x1b, wA1b, as1, ad1);
    fused_edge1<<<NN / 8, 256, 0, stream>>>(rs, deg, csr, x1b, as1, ad1, Bp1, b1, out);
}

// Round 8
// 310.038 us; speedup vs baseline: 1.1352x; 1.0025x over previous
//
#include <hip/hip_runtime.h>
#include <hip/hip_bf16.h>
#include <math.h>

#define NN 50000
#define NE 600000
#define NF 256
#define NHID 128
#define HEADS 8
#define D0 16
#define NCLS 64
#define NB1 196  // (NN+255)/256

#define PK0 (9 * 8 * 64 * 8)   // Bp0: 8 col-tiles of W0 + 1 alpha tile (W0A)
#define PK1 (4 * 32 * 64 * 8)  // Bp1
#define PKA (4 * 64 * 8)       // wA1b: K=128, N=16 (cols 0-7 wS heads, 8-15 wD)
#define PREPN (PK0 + PK1 + PKA)

typedef __attribute__((ext_vector_type(8))) short short8;
typedef __attribute__((ext_vector_type(4))) float floatx4;

__device__ __forceinline__ float bf16lo(uint v) { return __uint_as_float((v & 0xffffu) << 16); }
__device__ __forceinline__ float bf16hi(uint v) { return __uint_as_float(v & 0xffff0000u); }
__device__ __forceinline__ uint packbf16(float a, float b) {
    return (uint)__bfloat16_as_ushort(__float2bfloat16(a)) |
           ((uint)__bfloat16_as_ushort(__float2bfloat16(b)) << 16);
}
__device__ __forceinline__ short f2bf(float v) {
    return (short)__bfloat16_as_ushort(__float2bfloat16(v));
}
__device__ __forceinline__ float bf16tof(short v) {
    return __uint_as_float(((uint)(ushort)v) << 16);
}

// ---------------- CSR scan/scatter ----------------

__global__ void scan1_kernel(const int* __restrict__ deg, int* __restrict__ rs,
                             int* __restrict__ bsum) {
    __shared__ int sh[256];
    int tid = threadIdx.x;
    int i = blockIdx.x * 256 + tid;
    int v = (i < NN) ? deg[i] : 0;
    sh[tid] = v;
    __syncthreads();
    for (int off = 1; off < 256; off <<= 1) {
        int t = (tid >= off) ? sh[tid - off] : 0;
        __syncthreads();
        sh[tid] += t;
        __syncthreads();
    }
    if (i < NN) rs[i] = sh[tid] - v;  // exclusive
    if (tid == 255) bsum[blockIdx.x] = sh[255];
}

__global__ void scan2_kernel(const int* __restrict__ bsum, int* __restrict__ bsumx) {
    __shared__ int sh[256];
    int tid = threadIdx.x;
    int v = (tid < NB1) ? bsum[tid] : 0;
    sh[tid] = v;
    __syncthreads();
    for (int off = 1; off < 256; off <<= 1) {
        int t = (tid >= off) ? sh[tid - off] : 0;
        __syncthreads();
        sh[tid] += t;
        __syncthreads();
    }
    if (tid < NB1) bsumx[tid] = sh[tid] - v;
}

__global__ void scan3_kernel(int* __restrict__ rs, const int* __restrict__ bsumx) {
    int i = blockIdx.x * 256 + threadIdx.x;
    if (i < NN) rs[i] += bsumx[i >> 8];
}

__global__ void scatter_kernel(const int* __restrict__ ei, const int* __restrict__ rs,
                               int* __restrict__ cnt2, int* __restrict__ csr) {
    int e = blockIdx.x * 256 + threadIdx.x;
    if (e >= NE) return;
    int s = ei[e], d = ei[NE + e];
    int pos = rs[d] + atomicAdd(&cnt2[d], 1);
    csr[pos] = s;
}

// ---------------- fused degree + weight-prep (x-cast removed: gemm0 reads x
// directly and casts inline — deletes 51.2 MB read + 25.6 MB write + 25.6 MB
// re-read of xb from the pipeline) ----------------

__global__ void fused_prep_kernel(const int* __restrict__ ei, int* __restrict__ deg,
                                  const float* __restrict__ W0, const float* __restrict__ aS0,
                                  const float* __restrict__ aD0, const float* __restrict__ W1,
                                  const float* __restrict__ aS1, const float* __restrict__ aD1,
                                  short* __restrict__ Bp0, short* __restrict__ Bp1,
                                  short* __restrict__ wA1b) {
    int e = blockIdx.x * 256 + threadIdx.x;
    if (e < NE) {
        atomicAdd(&deg[ei[NE + e]], 1);
        return;
    }
    int tid = e - NE;
    if (tid < PK0) {
        int j = tid & 7, l = (tid >> 3) & 63, ks = (tid >> 9) & 7, t = tid >> 12;
        int k = ks * 32 + (l >> 4) * 8 + j;
        float v;
        if (t < 8) {
            int c = t * 16 + (l & 15);
            v = W0[(size_t)k * 128 + c];
        } else {  // alpha tile: col jj<8 -> as0 head jj; jj>=8 -> ad0 head jj-8
            int jj = l & 15;
            int hh = jj & 7;
            const float* av = (jj < 8) ? aS0 : aD0;
            float sum = 0.f;
            for (int dd = 0; dd < D0; ++dd)
                sum += W0[(size_t)k * 128 + hh * D0 + dd] * av[hh * D0 + dd];
            v = sum;
        }
        Bp0[tid] = f2bf(v);
    } else if (tid < PK0 + PK1) {
        int t2 = tid - PK0;
        int j = t2 & 7, l = (t2 >> 3) & 63, ks = (t2 >> 9) & 31, t = t2 >> 14;
        int kk = ks * 32 + (l >> 4) * 8 + j;
        int c = t * 16 + (l & 15);
        Bp1[t2] = f2bf(W1[(size_t)(kk & 127) * 512 + (kk >> 7) * 64 + c] * 0.125f);
    } else if (tid < PREPN) {
        // wA1b packed MFMA B-frag: K=128 (x1 dims), N=16: cols 0-7 = wS head c,
        // cols 8-15 = wD head c-8; w[h,k] = sum_d W1[k, h*64+d] * a1[h,d]
        int t3 = tid - PK0 - PK1;
        int j = t3 & 7, l = (t3 >> 3) & 63, ks = t3 >> 9;  // ks 0..3
        int k = ks * 32 + (l >> 4) * 8 + j;
        int c = l & 15;
        int h = c & 7;
        const float* av = (c < 8) ? aS1 : aD1;
        float sum = 0.f;
        for (int d2 = 0; d2 < NCLS; ++d2)
            sum += W1[(size_t)k * 512 + h * NCLS + d2] * av[h * NCLS + d2];
        wA1b[t3] = f2bf(sum);
    }
}

// ---------------- MFMA GEMMs ----------------

// h0b = bf16(x) @ W0 (bf16 out) AND as0/ad0 = bf16(x) @ W0A (alpha tile), fused.
// A-operand: f32 x loaded directly (2x float4) + inline f2bf — bit-identical
// to the old xb precast path.
__global__ __launch_bounds__(256) void gemm0_mfma(const float* __restrict__ x,
                                                  const short* __restrict__ Bp,
                                                  ushort* __restrict__ h0b,
                                                  float* __restrict__ as0,
                                                  float* __restrict__ ad0) {
    int lane = threadIdx.x & 63, wave = threadIdx.x >> 6;
    int rg = wave >> 1, cg = wave & 1;
    int q = lane >> 4, c16 = lane & 15;
    int row0 = blockIdx.x * 32 + rg * 16;
    int arow = row0 + c16;
    if (arow > NN - 1) arow = NN - 1;
    const float* ap = x + (size_t)arow * NF + q * 8;
    floatx4 acc[5] = {};
#pragma unroll
    for (int ks = 0; ks < 8; ++ks) {
        float4 va = *(const float4*)(ap + ks * 32);
        float4 vb = *(const float4*)(ap + ks * 32 + 4);
        short8 af;
        af[0] = f2bf(va.x); af[1] = f2bf(va.y); af[2] = f2bf(va.z); af[3] = f2bf(va.w);
        af[4] = f2bf(vb.x); af[5] = f2bf(vb.y); af[6] = f2bf(vb.z); af[7] = f2bf(vb.w);
#pragma unroll
        for (int tt = 0; tt < 4; ++tt) {
            int t = cg * 4 + tt;
            short8 bf = *(const short8*)(Bp + (((size_t)t * 8 + ks) * 64 + lane) * 8);
            acc[tt] = __builtin_amdgcn_mfma_f32_16x16x32_bf16(af, bf, acc[tt], 0, 0, 0);
        }
        if (cg) {  // wave-uniform: alpha tile t=8
            short8 bf = *(const short8*)(Bp + (((size_t)8 * 8 + ks) * 64 + lane) * 8);
            acc[4] = __builtin_amdgcn_mfma_f32_16x16x32_bf16(af, bf, acc[4], 0, 0, 0);
        }
    }
#pragma unroll
    for (int r = 0; r < 4; ++r) {
        int grow = row0 + q * 4 + r;
        if (grow >= NN) continue;
#pragma unroll
        for (int tt = 0; tt < 4; ++tt)
            h0b[(size_t)grow * NHID + cg * 64 + tt * 16 + c16] =
                (ushort)f2bf(acc[tt][r]);
        if (cg) {
            float v = acc[4][r];
            if (c16 < 8) as0[grow * 8 + c16] = v;
            else         ad0[grow * 8 + (c16 - 8)] = v;
        }
    }
}

// as1/ad1 = x1b @ wA1b  (tiny MFMA: 16 rows/wave, K=128, N=16)
__global__ __launch_bounds__(256) void alpha1_mfma(const ushort* __restrict__ x1b,
                                                   const short* __restrict__ wA1b,
                                                   float* __restrict__ as1,
                                                   float* __restrict__ ad1) {
    int lane = threadIdx.x & 63, wave = threadIdx.x >> 6;
    int q = lane >> 4, c16 = lane & 15;
    int row0 = blockIdx.x * 64 + wave * 16;
    int arow = row0 + c16;
    if (arow > NN - 1) arow = NN - 1;
    const short* ap = (const short*)x1b + (size_t)arow * NHID + q * 8;
    floatx4 acc = {};
#pragma unroll
    for (int ks = 0; ks < 4; ++ks) {
        short8 af = *(const short8*)(ap + ks * 32);
        short8 bf = *(const short8*)(wA1b + (((size_t)ks) * 64 + lane) * 8);
        acc = __builtin_amdgcn_mfma_f32_16x16x32_bf16(af, bf, acc, 0, 0, 0);
    }
#pragma unroll
    for (int r = 0; r < 4; ++r) {
        int grow = row0 + q * 4 + r;
        if (grow >= NN) continue;
        float v = acc[r];
        if (c16 < 8) as1[grow * 8 + c16] = v;
        else         ad1[grow * 8 + (c16 - 8)] = v;
    }
}

// ---------------- fused edge kernels ----------------
// softmax without max subtraction (shift-invariant; logits O(+-6)).

// Layer 0: one wave per dst, 16-deep chunks (two 8-edge alpha groups, all 16
// gathers issued before first use -> 16-deep MLP, one iteration for deg<=16).
__global__ __launch_bounds__(256) void fused_edge0(
    const int* __restrict__ rs, const int* __restrict__ deg, const int* __restrict__ csr,
    const ushort* __restrict__ h0b, const float* __restrict__ as0, const float* __restrict__ ad0,
    const float* __restrict__ b0, ushort* __restrict__ x1b) {
    int d = (blockIdx.x * 256 + threadIdx.x) >> 6;
    int lane = threadIdx.x & 63;
    if (d >= NN) return;
    int row = rs[d], dg = deg[d];
    int hl = lane & 7, g = lane >> 3;
    int hp = lane >> 3;  // head owning this lane's dim pair
    float adv = ad0[d * 8 + hl];
    float den = 0.f;
    float2 acc = {0.f, 0.f};
    for (int base = 0; base < dg; base += 16) {
        int i0 = base + g, i1 = base + 8 + g;
        int s0 = (i0 < dg) ? csr[row + i0] : 0;
        int s1 = (i1 < dg) ? csr[row + i1] : 0;
        float ev0 = as0[s0 * 8 + hl] + adv;
        ev0 = ev0 > 0.f ? ev0 : 0.2f * ev0;
        float p0 = (i0 < dg) ? __expf(ev0) : 0.f;
        float ev1 = as0[s1 * 8 + hl] + adv;
        ev1 = ev1 > 0.f ? ev1 : 0.2f * ev1;
        float p1 = (i1 < dg) ? __expf(ev1) : 0.f;
        den += p0 + p1;
        uint vbuf[16];
#pragma unroll
        for (int g2 = 0; g2 < 8; ++g2) {
            int sg = __builtin_amdgcn_readlane(s0, g2 * 8);  // scalar base
            vbuf[g2] = *(const uint*)(h0b + (size_t)sg * NHID + 2 * lane);
        }
#pragma unroll
        for (int g2 = 0; g2 < 8; ++g2) {
            int sg = __builtin_amdgcn_readlane(s1, g2 * 8);
            vbuf[8 + g2] = *(const uint*)(h0b + (size_t)sg * NHID + 2 * lane);
        }
#pragma unroll
        for (int g2 = 0; g2 < 8; ++g2) {
            float ph = __shfl(p0, g2 * 8 + hp);  // hp per-lane -> bpermute
            acc.x += bf16lo(vbuf[g2]) * ph;
            acc.y += bf16hi(vbuf[g2]) * ph;
        }
#pragma unroll
        for (int g2 = 0; g2 < 8; ++g2) {
            float ph = __shfl(p1, g2 * 8 + hp);
            acc.x += bf16lo(vbuf[8 + g2]) * ph;
            acc.y += bf16hi(vbuf[8 + g2]) * ph;
        }
    }
    den += __shfl_xor(den, 8);
    den += __shfl_xor(den, 16);
    den += __shfl_xor(den, 32);
    float dh = __shfl(den, hp);
    float inv = 1.f / (dh + 1e-16f);
    float2 bb = ((const float2*)b0)[lane];
    float o0 = acc.x * inv + bb.x;
    float o1 = acc.y * inv + bb.y;
    o0 = o0 > 0.f ? o0 : expf(o0) - 1.f;
    o1 = o1 > 0.f ? o1 : expf(o1) - 1.f;
    *(uint*)(x1b + (size_t)d * NHID + 2 * lane) = packbf16(o0, o1);
}

// Layer 1: MFMA aggregation + BLOCK-COOPERATIVE output GEMM + log_softmax.
// EXACT r4 structure (proven 88 us). aggNsh stride 1032 shorts = 2064 B:
// 16B-ALIGNED (short8 ds_read_b128 requires it — r7's 1036 misaligned and
// cost +7 us despite fewer bank conflicts).
// Block = 4 waves = 8 dsts (wave w owns dA=2*(blk*4+w), dB=dA+1). Grid 6250
// exact: no early returns -> barriers legal.
// Stage 1 (per wave): one mfma per 16-col tile;
//   A[m,k] = alpha_bf16[dst=(m<8?A:B), head=m&7], zero when (m<8)!=(k<16)
//   B[k,n] = x1b[src[edge k], n] gathered in B-frag layout (2B loads = transpose)
// Stage 2 (cooperative, ks-split): wave w does ks = w*8..w*8+7, all 4 t-tiles
// (af2 loaded once per ks, reused 4x; acc2[4] = 4 independent MFMA chains).
// Partial C staged to Csh[4][8][64], reduced in 64-lane epilogue (lane=class).
__global__ __launch_bounds__(256) void fused_edge1(
    const int* __restrict__ rs, const int* __restrict__ deg, const int* __restrict__ csr,
    const ushort* __restrict__ x1b, const float* __restrict__ as1, const float* __restrict__ ad1,
    const short* __restrict__ Bp1, const float* __restrict__ b1, float* __restrict__ out) {
    __shared__ ushort aggNsh[8][1032];  // 16.5 KB, rows 16B-aligned
    __shared__ float Csh[4][8][64];     // 8 KB partial C
    int wave = threadIdx.x >> 6;
    int lane = threadIdx.x & 63;
    int gw = blockIdx.x * 4 + wave;
    int dA = 2 * gw;
    int dB = dA + 1;
    int q = lane >> 4, c16 = lane & 15, h7 = lane & 7;
    int d_l = (lane >= 32) ? dB : dA;
    int row_l = rs[d_l], dg_l = deg[d_l];
    // A-frag validity: (m<8) == (k<16)  <=>  ((lane&8)==0) == (lane<32)
    bool V = ((lane & 8) == 0) == (lane < 32);
    float adv = ad1[d_l * 8 + h7];
    int dgA = __shfl(dg_l, 0);
    int dgB = __shfl(dg_l, 32);
    int dgmax = dgA > dgB ? dgA : dgB;
    float den = 0.f;
    floatx4 acc[8] = {};
    for (int base = 0; base < dgmax; base += 16) {
        short8 af;
        int sarr[8];
#pragma unroll
        for (int j = 0; j < 8; ++j) {
            int idx = base + (q & 1) * 8 + j;  // edge slot within this lane's dst
            int s = 0;
            if (idx < dg_l) s = csr[row_l + idx];
            sarr[j] = s;
            float ev = as1[s * 8 + h7] + adv;
            ev = ev > 0.f ? ev : 0.2f * ev;
            float p = __expf(ev);
            p = (idx < dg_l && V) ? p : 0.f;
            short pb = f2bf(p);
            af[j] = pb;
            den += bf16tof(pb);  // den over bf16-rounded alpha (matches MFMA)
        }
#pragma unroll
        for (int t = 0; t < 8; ++t) {
            short8 bv;
#pragma unroll
            for (int j = 0; j < 8; ++j)
                bv[j] = (short)x1b[(size_t)sarr[j] * NHID + t * 16 + c16];
            acc[t] = __builtin_amdgcn_mfma_f32_16x16x32_bf16(af, bv, acc[t], 0, 0, 0);
        }
    }
    // den per (dst, head): valid partials live at lanes {h, h+16} of each half
    den += __shfl_xor(den, 8);
    den += __shfl_xor(den, 16);
    // normalize + stage to LDS: C[m = q*4+r, n = t*16+c16]
    int hbase = (q & 1) * 4;
    int lrow = wave * 2 + (lane >> 5);  // local dst row 0..7 = global dst blk*8+lrow
#pragma unroll
    for (int r = 0; r < 4; ++r) {
        int hh = hbase + r;
        float dh = __shfl(den, (lane & 32) + hh);
        float inv = 1.f / (dh + 1e-16f);
#pragma unroll
        for (int t = 0; t < 8; ++t)
            aggNsh[lrow][hh * 128 + t * 16 + c16] = (ushort)f2bf(acc[t][r] * inv);
    }
    __syncthreads();
    // ---- stage 2: cooperative GEMM, wave w covers ks in [w*8, w*8+8) ----
    {
        floatx4 acc2[4] = {};
        const short* abase = (const short*)&aggNsh[c16 & 7][0];
        int ks0 = wave * 8;
#pragma unroll
        for (int kk = 0; kk < 8; ++kk) {
            int ks = ks0 + kk;
            short8 af2 = *(const short8*)(abase + ks * 32 + q * 8);
#pragma unroll
            for (int t = 0; t < 4; ++t) {
                short8 bf = *(const short8*)(Bp1 + (((size_t)t * 32 + ks) * 64 + lane) * 8);
                acc2[t] = __builtin_amdgcn_mfma_f32_16x16x32_bf16(af2, bf, acc2[t], 0, 0, 0);
            }
        }
        if (q < 2) {  // rows m = q*4+r in 0..7 are valid
#pragma unroll
            for (int r = 0; r < 4; ++r)
#pragma unroll
                for (int t = 0; t < 4; ++t)
                    Csh[wave][q * 4 + r][t * 16 + c16] = acc2[t][r];
        }
    }
    __syncthreads();
    // ---- epilogue: wave w finishes its own dsts (local rows 2w, 2w+1) ----
    float z0 = 0.f, z1 = 0.f;
#pragma unroll
    for (int w2 = 0; w2 < 4; ++w2) {
        z0 += Csh[w2][wave * 2][lane];
        z1 += Csh[w2][wave * 2 + 1][lane];
    }
    float bb = b1[lane];
    z0 += bb;
    z1 += bb;
    float mx0 = z0, mx1 = z1;
#pragma unroll
    for (int x = 1; x < 64; x <<= 1) {
        mx0 = fmaxf(mx0, __shfl_xor(mx0, x));
        mx1 = fmaxf(mx1, __shfl_xor(mx1, x));
    }
    float s0 = expf(z0 - mx0), s1 = expf(z1 - mx1);
#pragma unroll
    for (int x = 1; x < 64; x <<= 1) {
        s0 += __shfl_xor(s0, x);
        s1 += __shfl_xor(s1, x);
    }
    float lse0 = mx0 + logf(s0);
    float lse1 = mx1 + logf(s1);
    out[(size_t)dA * NCLS + lane] = z0 - lse0;
    out[(size_t)dB * NCLS + lane] = z1 - lse1;
}

// ---------------- launch ----------------

extern "C" void kernel_launch(void* const* d_in, const int* in_sizes, int n_in,
                              void* d_out, int out_size, void* d_ws, size_t ws_size,
                              hipStream_t stream) {
    const float* x   = (const float*)d_in[0];
    const int*   ei  = (const int*)d_in[1];
    const float* W0  = (const float*)d_in[2];
    const float* aS0 = (const float*)d_in[3];
    const float* aD0 = (const float*)d_in[4];
    const float* b0  = (const float*)d_in[5];
    const float* W1  = (const float*)d_in[6];
    const float* aS1 = (const float*)d_in[7];
    const float* aD1 = (const float*)d_in[8];
    const float* b1  = (const float*)d_in[9];
    float* out = (float*)d_out;

    char* ws = (char*)d_ws;
    ushort* x1b = (ushort*)ws; ws += (size_t)NN * NHID * 2;           // 12.8 MB
    ushort* h0b = (ushort*)ws; ws += (size_t)NN * NHID * 2;           // 12.8 MB
    float* as0  = (float*)ws; ws += (size_t)NN * HEADS * 4;
    float* ad0  = (float*)ws; ws += (size_t)NN * HEADS * 4;
    float* as1  = (float*)ws; ws += (size_t)NN * HEADS * 4;
    float* ad1  = (float*)ws; ws += (size_t)NN * HEADS * 4;
    short* Bp0  = (short*)ws; ws += (size_t)PK0 * 2;
    short* Bp1  = (short*)ws; ws += (size_t)PK1 * 2;
    short* wA1b = (short*)ws; ws += (size_t)PKA * 2;
    int* deg    = (int*)ws; ws += (size_t)NN * 4;
    int* cnt2   = (int*)ws; ws += (size_t)NN * 4;                     // adjacent to deg
    int* rs     = (int*)ws; ws += (size_t)NN * 4;
    int* bsum   = (int*)ws; ws += 256 * 4;
    int* bsumx  = (int*)ws; ws += 256 * 4;
    int* csr    = (int*)ws; ws += (size_t)NE * 4;                     // 2.4 MB

    const int FUSEDN = NE + PREPN;

    // ---- zero deg + cnt2, then fused degree/weight-prep ----
    hipMemsetAsync(deg, 0, (size_t)2 * NN * 4, stream);
    fused_prep_kernel<<<(FUSEDN + 255) / 256, 256, 0, stream>>>(
        ei, deg, W0, aS0, aD0, W1, aS1, aD1, Bp0, Bp1, wA1b);

    // ---- CSR scan + scatter ----
    scan1_kernel<<<NB1, 256, 0, stream>>>(deg, rs, bsum);
    scan2_kernel<<<1, 256, 0, stream>>>(bsum, bsumx);
    scan3_kernel<<<NB1, 256, 0, stream>>>(rs, bsumx);
    scatter_kernel<<<(NE + 255) / 256, 256, 0, stream>>>(ei, rs, cnt2, csr);

    // ---- layer 0 (gemm0 reads x f32 directly, inline bf16 cast) ----
    gemm0_mfma<<<(NN + 31) / 32, 256, 0, stream>>>(x, Bp0, h0b, as0, ad0);
    fused_edge0<<<(NN + 3) / 4, 256, 0, stream>>>(rs, deg, csr, h0b, as0, ad0, b0, x1b);

    // ---- layer 1 (aggregation + cooperative output GEMM + log_softmax fused) ----
    alpha1_mfma<<<(NN + 63) / 64, 256, 0, stream>>>(x1b, wA1b, as1, ad1);
    fused_edge1<<<NN / 8, 256, 0, stream>>>(rs, deg, csr, x1b, as1, ad1, Bp1, b1, out);
}